// Round 8
// baseline (255.766 us; speedup 1.0000x reference)
//
#include <hip/hip_runtime.h>
#include <hip/hip_bf16.h>

#define GG 64      // B*N graphs
#define LN 2048    // nodes per graph
#define BB 4       // batch
#define NS 16      // sets per batch
#define EE 16384   // edges
#define C_0 64
#define CH 128
#define EPSV 1e-5f
#define VK 16      // variance atomic spread copies
#define GNB 8      // nodes per k_gnv chunk
#define ECAP 384   // staged-edge capacity per chunk (mean 64; global fallback beyond)
// sliced layout: 8 slices of (32 graphs x 32 ch); slice id = (g>>5)*4 + (c>>5)
// elem addr = sid*SLICE + l*1024 + (g&31)*32 + (c&31)
#define SLICE ((size_t)LN * 1024)

using bf16x8 = __attribute__((ext_vector_type(8))) short;
using f32x4  = __attribute__((ext_vector_type(4))) float;
using u32x4  = __attribute__((ext_vector_type(4))) unsigned int;
typedef unsigned long long ull;

__device__ __forceinline__ float b2f(unsigned short u) {
    union { unsigned int i; float f; } v; v.i = ((unsigned int)u) << 16; return v.f;
}
__device__ __forceinline__ unsigned short f2b(float f) {
    union { float f; unsigned int i; } v; v.f = f;
    unsigned int r = v.i + 0x7fffu + ((v.i >> 16) & 1u);   // RNE
    return (unsigned short)(r >> 16);
}
__device__ __forceinline__ void acc8(float* acc, u32x4 v, float w) {
    acc[0] += w * b2f((unsigned short)(v.x & 0xffffu));
    acc[1] += w * b2f((unsigned short)(v.x >> 16));
    acc[2] += w * b2f((unsigned short)(v.y & 0xffffu));
    acc[3] += w * b2f((unsigned short)(v.y >> 16));
    acc[4] += w * b2f((unsigned short)(v.z & 0xffffu));
    acc[5] += w * b2f((unsigned short)(v.z >> 16));
    acc[6] += w * b2f((unsigned short)(v.w & 0xffffu));
    acc[7] += w * b2f((unsigned short)(v.w >> 16));
}
// W permute: element (k,c) -> Wp[(ks*8+nf)*512 + (hi*16+lr)*8 + j]
__device__ __forceinline__ void wprep_one(const float* __restrict__ W,
                                          unsigned short* __restrict__ Wp, int idx) {
    int k = idx >> 7, c = idx & (CH - 1);
    int nf = c >> 4, lr = c & 15, ks = k >> 5, hi = (k >> 3) & 3, j = k & 7;
    Wp[(ks * 8 + nf) * 512 + (hi * 16 + lr) * 8 + j] = f2b(W[idx]);
}

// ---------- consolidated preprocessing: 7 blocks ----------
// block 0: degree -> dinv/selfc -> CSR scan -> packed edge fill (all in LDS)
// block 1: Wp1; blocks 2-3: Wp2; blocks 4-5: Wp3; block 6: zero varK arena
__global__ __launch_bounds__(256) void k_prep(
    const int* __restrict__ src, const int* __restrict__ dst,
    const float* __restrict__ W1, const float* __restrict__ W2,
    const float* __restrict__ W3,
    float* __restrict__ selfc, int* __restrict__ off, ull* __restrict__ epack,
    unsigned short* __restrict__ Wp1, unsigned short* __restrict__ Wp2,
    unsigned short* __restrict__ Wp3, float* __restrict__ varK3)
{
    const int bid = blockIdx.x;
    const int t = threadIdx.x;
    if (bid == 0) {
        __shared__ int cntL[LN];          // then reused as cur
        __shared__ float dinvL[LN];
        __shared__ int offL[LN + 1];
        __shared__ int part[256];
        __shared__ int pre2[256];
        for (int i = t; i < LN; i += 256) cntL[i] = 0;
        __syncthreads();
        for (int e = t; e < EE; e += 256) atomicAdd(&cntL[dst[e]], 1);
        __syncthreads();
        for (int i = t; i < LN; i += 256) {
            float d = (float)cntL[i] + 2.0f;   // improved GCN: A + 2I
            float di = rsqrtf(d);
            dinvL[i] = di;
            selfc[i] = 2.0f * di * di;
        }
        // scan
        {
            const int base = t * 8;
            int loc[8];
            int s = 0;
#pragma unroll
            for (int i = 0; i < 8; i++) { loc[i] = cntL[base + i]; s += loc[i]; }
            part[t] = s;
            __syncthreads();
            if (t == 0) {
                int run = 0;
                for (int i = 0; i < 256; i++) { pre2[i] = run; run += part[i]; }
                offL[LN] = run;
                off[LN] = run;
            }
            __syncthreads();
            int run = pre2[t];
#pragma unroll
            for (int i = 0; i < 8; i++) {
                offL[base + i] = run;
                off[base + i] = run;
                run += loc[i];
            }
        }
        __syncthreads();
        for (int i = t; i < LN; i += 256) cntL[i] = 0;   // cur
        __syncthreads();
        for (int e = t; e < EE; e += 256) {
            int s = src[e], d = dst[e];
            int pos = atomicAdd(&cntL[d], 1);
            union { float f; unsigned u; } w;
            w.f = dinvL[s] * dinvL[d];
            epack[offL[d] + pos] = (ull)(unsigned)s | ((ull)w.u << 32);
        }
    } else if (bid == 1) {
        for (int i = t; i < C_0 * CH; i += 256) wprep_one(W1, Wp1, i);
    } else if (bid <= 3) {
        const int base = (bid - 2) * 8192;
        for (int i = t; i < 8192; i += 256) wprep_one(W2, Wp2, base + i);
    } else if (bid <= 5) {
        const int base = (bid - 4) * 8192;
        for (int i = t; i < 8192; i += 256) wprep_one(W3, Wp3, base + i);
    } else {
        for (int i = t; i < 3 * VK * CH; i += 256) varK3[i] = 0.f;
    }
}

// ---------- MFMA GEMM: hw[l,g,co] = sum_k A[l,k] * W[k,co] (bf16, fp32 acc) ----------
// FUSE=false: layer 1, A from x fp32 [g][K][LN] via LDS transpose.
// FUSE=true : A-fragment direct from sliced global aB (16B/lane contiguous);
//             previous layer's BN scale computed in-block from varK, BN+ReLU in regs.
template <int K, bool FUSE>
__global__ __launch_bounds__(256) void k_mm(
    const float* __restrict__ X, const unsigned short* __restrict__ Ap,
    const float* __restrict__ varKp, const float* __restrict__ gam,
    const float* __restrict__ bet,
    const unsigned short* __restrict__ Wp, unsigned short* __restrict__ hw)
{
    constexpr int KP = K + 8;                 // LDS k-pad (!FUSE staging)
    __shared__ unsigned short As[64 * 136];   // A tile (!FUSE) / C repack buffer
    __shared__ float sclL[CH];
    const int g = blockIdx.y;
    const int l0 = blockIdx.x * 64;
    const int t = threadIdx.x;
    const int wq = t >> 6;
    const int lane = t & 63;
    const int lr = lane & 15;
    const int hi = lane >> 4;
    const int kof = hi * 8;

    f32x4 acc[8];
#pragma unroll
    for (int i = 0; i < 8; i++) acc[i] = (f32x4){0.f, 0.f, 0.f, 0.f};

    if (FUSE) {
        if (t < CH) {
            float v = 0.f;
#pragma unroll
            for (int k = 0; k < VK; k++) v += varKp[k * CH + t];
            sclL[t] = gam[t] * rsqrtf(v * (1.f / (GG * LN)) + EPSV);
        }
        __syncthreads();
        const int sg = g >> 5;
        const int gi = g & 31;
        const int row = l0 + wq * 16 + lr;
        bf16x8 aF[K / 32];
#pragma unroll
        for (int ks = 0; ks < K / 32; ks++) {
            const unsigned short* ap = Ap + (size_t)(sg * 4 + ks) * SLICE +
                                       (size_t)row * 1024 + gi * 32 + kof;
            union { uint4 v; unsigned short s[8]; } u;
            u.v = *(const uint4*)ap;
            const int cb = ks * 32 + kof;
            float4 s0 = *(const float4*)&sclL[cb];
            float4 s1 = *(const float4*)&sclL[cb + 4];
            float4 c0 = *(const float4*)&bet[cb];
            float4 c1 = *(const float4*)&bet[cb + 4];
            union { bf16x8 f; unsigned short s[8]; } o;
            o.s[0] = f2b(fmaxf(b2f(u.s[0]) * s0.x + c0.x, 0.f));
            o.s[1] = f2b(fmaxf(b2f(u.s[1]) * s0.y + c0.y, 0.f));
            o.s[2] = f2b(fmaxf(b2f(u.s[2]) * s0.z + c0.z, 0.f));
            o.s[3] = f2b(fmaxf(b2f(u.s[3]) * s0.w + c0.w, 0.f));
            o.s[4] = f2b(fmaxf(b2f(u.s[4]) * s1.x + c1.x, 0.f));
            o.s[5] = f2b(fmaxf(b2f(u.s[5]) * s1.y + c1.y, 0.f));
            o.s[6] = f2b(fmaxf(b2f(u.s[6]) * s1.z + c1.z, 0.f));
            o.s[7] = f2b(fmaxf(b2f(u.s[7]) * s1.w + c1.w, 0.f));
            aF[ks] = o.f;
        }
#pragma unroll
        for (int ks = 0; ks < K / 32; ks++) {
#pragma unroll
            for (int nf = 0; nf < 8; nf++) {
                bf16x8 bF = *(const bf16x8*)&Wp[(ks * 8 + nf) * 512 + lane * 8];
                acc[nf] = __builtin_amdgcn_mfma_f32_16x16x32_bf16(aF[ks], bF,
                                                                  acc[nf], 0, 0, 0);
            }
        }
    } else {
        // x fp32 [g][K][LN] -> As[l][k] bf16 (transpose in LDS)
        const int k = t >> 2;
        const int lq = (t & 3) * 16;
        const float* xp = X + ((size_t)g * K + k) * LN + l0 + lq;
#pragma unroll
        for (int i = 0; i < 16; i += 4) {
            float4 v = *(const float4*)&xp[i];
            As[(lq + i + 0) * KP + k] = f2b(v.x);
            As[(lq + i + 1) * KP + k] = f2b(v.y);
            As[(lq + i + 2) * KP + k] = f2b(v.z);
            As[(lq + i + 3) * KP + k] = f2b(v.w);
        }
        __syncthreads();
#pragma unroll
        for (int ks = 0; ks < K / 32; ks++) {
            bf16x8 aF = *(const bf16x8*)&As[(wq * 16 + lr) * KP + ks * 32 + kof];
#pragma unroll
            for (int nf = 0; nf < 8; nf++) {
                bf16x8 bF = *(const bf16x8*)&Wp[(ks * 8 + nf) * 512 + lane * 8];
                acc[nf] = __builtin_amdgcn_mfma_f32_16x16x32_bf16(aF, bF,
                                                                  acc[nf], 0, 0, 0);
            }
        }
        __syncthreads();   // As about to be overwritten by C repack
    }
    // repack D (C/D map: col=lane&15, row=(lane>>4)*4+reg) into As
#pragma unroll
    for (int nf = 0; nf < 8; nf++) {
#pragma unroll
        for (int r = 0; r < 4; r++) {
            int row = wq * 16 + (lane >> 4) * 4 + r;
            int col = nf * 16 + lr;
            As[row * 136 + col] = f2b(acc[nf][r]);
        }
    }
    __syncthreads();
    {
        const int l = t >> 2;
        const int sc = t & 3;
        unsigned short* hp = hw + (size_t)((g >> 5) * 4 + sc) * SLICE +
                             (size_t)(l0 + l) * 1024 + (g & 31) * 32;
#pragma unroll
        for (int i = 0; i < 32; i += 8)
            *(uint4*)&hp[i] = *(const uint4*)&As[l * 136 + sc * 32 + i];
    }
}

// ---------- fused gather + center + variance, XCD-pinned slices ----------
// bid = chunk*8 + sid; GNB nodes per chunk; 256 threads = 2 rows x 128 lanes (16B)
// edge metadata staged in LDS up front -> gather addresses have no global dependency
__global__ __launch_bounds__(256) void k_gnv(
    const unsigned short* __restrict__ hw, unsigned short* __restrict__ a,
    float* __restrict__ varK, const int* __restrict__ off,
    const ull* __restrict__ epack, const float* __restrict__ selfc)
{
    __shared__ ull emeta[ECAP];
    __shared__ int soff[GNB + 1];
    __shared__ float sselfc[GNB];
    __shared__ float vred[4][32];
    const int bid = blockIdx.x;
    const int sid = bid & 7;
    const int chunk = bid >> 3;          // [0, LN/GNB)
    const int l0 = chunk * GNB;
    const int t = threadIdx.x;
    const int tr = t >> 7;
    const int ti = t & 127;
    const int lane = t & 63;
    const int wq = t >> 6;
    const int go = ti * 8;               // short offset within 1024-short row
    const unsigned short* hws = hw + sid * SLICE;
    unsigned short* aBs = a + sid * SLICE;

    // prefetch self rows (independent of LDS)
    u32x4 v0s[GNB / 2];
#pragma unroll
    for (int ii = 0; ii < GNB / 2; ii++)
        v0s[ii] = *(const u32x4*)&hws[(size_t)(l0 + ii * 2 + tr) * 1024 + go];

    // stage metadata
    const int e0 = off[l0];
    const int eTot = off[l0 + GNB] - e0;
    if (t <= GNB) soff[t] = off[l0 + t];
    if (t >= 32 && t < 32 + GNB) sselfc[t - 32] = selfc[l0 + t - 32];
    const int estg = eTot < ECAP ? eTot : ECAP;
    for (int i = t; i < estg; i += 256) emeta[i] = epack[e0 + i];
    __syncthreads();

    float vacc[8] = {0.f, 0.f, 0.f, 0.f, 0.f, 0.f, 0.f, 0.f};

    auto gather = [&](const ull* __restrict__ mp) {
#pragma unroll
        for (int ii = 0; ii < GNB / 2; ii++) {
            const int ln = ii * 2 + tr;
            const int l = l0 + ln;
            const int s0 = soff[ln] - e0;
            const int s1 = soff[ln + 1] - e0;
            const float sc = sselfc[ln];
            float acc[8];
            {
                u32x4 v0 = v0s[ii];
                acc[0] = sc * b2f((unsigned short)(v0.x & 0xffffu));
                acc[1] = sc * b2f((unsigned short)(v0.x >> 16));
                acc[2] = sc * b2f((unsigned short)(v0.y & 0xffffu));
                acc[3] = sc * b2f((unsigned short)(v0.y >> 16));
                acc[4] = sc * b2f((unsigned short)(v0.z & 0xffffu));
                acc[5] = sc * b2f((unsigned short)(v0.z >> 16));
                acc[6] = sc * b2f((unsigned short)(v0.w & 0xffffu));
                acc[7] = sc * b2f((unsigned short)(v0.w >> 16));
            }
            int e = s0;
            for (; e + 4 <= s1; e += 4) {
                ull m0 = mp[e], m1 = mp[e + 1], m2 = mp[e + 2], m3 = mp[e + 3];
                u32x4 vA = *(const u32x4*)&hws[(size_t)(unsigned)m0 * 1024 + go];
                u32x4 vB = *(const u32x4*)&hws[(size_t)(unsigned)m1 * 1024 + go];
                u32x4 vC = *(const u32x4*)&hws[(size_t)(unsigned)m2 * 1024 + go];
                u32x4 vD = *(const u32x4*)&hws[(size_t)(unsigned)m3 * 1024 + go];
                acc8(acc, vA, __uint_as_float((unsigned)(m0 >> 32)));
                acc8(acc, vB, __uint_as_float((unsigned)(m1 >> 32)));
                acc8(acc, vC, __uint_as_float((unsigned)(m2 >> 32)));
                acc8(acc, vD, __uint_as_float((unsigned)(m3 >> 32)));
            }
            for (; e < s1; e++) {
                ull m0 = mp[e];
                u32x4 vA = *(const u32x4*)&hws[(size_t)(unsigned)m0 * 1024 + go];
                acc8(acc, vA, __uint_as_float((unsigned)(m0 >> 32)));
            }
            // mean over the 16 sets (n-index = lane bits 2..5)
            float m[8];
#pragma unroll
            for (int j = 0; j < 8; j++) m[j] = acc[j];
#pragma unroll
            for (int mask = 4; mask <= 32; mask <<= 1) {
#pragma unroll
                for (int j = 0; j < 8; j++) m[j] += __shfl_xor(m[j], mask);
            }
            u32x4 o;
            unsigned short ob[8];
#pragma unroll
            for (int j = 0; j < 8; j++) {
                float d = acc[j] - m[j] * (1.f / NS);   // centered value
                vacc[j] += d * d;
                ob[j] = f2b(d);
            }
            o.x = (unsigned int)ob[0] | ((unsigned int)ob[1] << 16);
            o.y = (unsigned int)ob[2] | ((unsigned int)ob[3] << 16);
            o.z = (unsigned int)ob[4] | ((unsigned int)ob[5] << 16);
            o.w = (unsigned int)ob[6] | ((unsigned int)ob[7] << 16);
            __builtin_nontemporal_store(o, (u32x4*)&aBs[(size_t)l * 1024 + go]);
        }
    };
    if (eTot <= ECAP) gather(emeta);
    else gather(epack + e0);           // pathological-degree fallback (never in practice)

    // variance: butterfly within wave, cross-wave LDS reduce, 32 atomics/block
#pragma unroll
    for (int mask = 4; mask <= 32; mask <<= 1) {
#pragma unroll
        for (int j = 0; j < 8; j++) vacc[j] += __shfl_xor(vacc[j], mask);
    }
    if (lane < 4) {
#pragma unroll
        for (int j = 0; j < 8; j++) vred[wq][lane * 8 + j] = vacc[j];
    }
    __syncthreads();
    if (t < 32) {
        float s = vred[0][t] + vred[1][t] + vred[2][t] + vred[3][t];
        atomicAdd(&varK[(chunk & (VK - 1)) * CH + (sid & 3) * 32 + t], s);
    }
}

// ---------- final epilogue: sliced centered bf16 -> out[g][c][l] fp32 ----------
// bid = ((chunk*2 + gh)*8) + sid; chunk picks 32 nodes, gh picks 16-graph half
// 128B fully-coalesced output segments; BN scale computed in-block from varK
__global__ __launch_bounds__(256) void k_epi_t(
    const unsigned short* __restrict__ a, const float* __restrict__ varKp,
    const float* __restrict__ gam, const float* __restrict__ bet,
    float* __restrict__ out)
{
    __shared__ unsigned short lds[32 * 16 * 40];   // [l][g][c pad40], 40KB
    __shared__ float sclL[CH];
    const int bid = blockIdx.x;
    const int sid = bid & 7;
    const int q = bid >> 3;              // chunk*2 + gh
    const int gh = q & 1;
    const int chunk = q >> 1;            // [0,64)
    const int l0 = chunk * 32;
    const int t = threadIdx.x;
    const int sg = sid >> 2;
    const int sc = sid & 3;
    const unsigned short* aBs = a + sid * SLICE;
    if (t < CH) {
        float v = 0.f;
#pragma unroll
        for (int k = 0; k < VK; k++) v += varKp[k * CH + t];
        sclL[t] = gam[t] * rsqrtf(v * (1.f / (GG * LN)) + EPSV);
    }
    {
        const int qr = t >> 6;           // 4 rows in flight
        const int ti = t & 63;
        const int gl = ti >> 2;
        const int c0 = (ti & 3) * 8;
#pragma unroll
        for (int i = 0; i < 8; i++) {
            const int lrow = i * 4 + qr;
            uint4 v = *(const uint4*)&aBs[(size_t)(l0 + lrow) * 1024 + gh * 512 + ti * 8];
            *(uint4*)&lds[(lrow * 16 + gl) * 40 + c0] = v;
        }
    }
    __syncthreads();
#pragma unroll
    for (int it = 0; it < 2; it++) {
        const int p = it * 256 + t;
        const int g2 = p >> 5;           // [0,16)
        const int c2 = p & 31;
        const int cG = sc * 32 + c2;
        const int gG = sg * 32 + gh * 16 + g2;
        const float s = sclL[cG], bb = bet[cG];
        float o[32];
#pragma unroll
        for (int l = 0; l < 32; l++)
            o[l] = fmaxf(b2f(lds[(l * 16 + g2) * 40 + c2]) * s + bb, 0.f);
        float* op = &out[((size_t)gG * CH + cG) * LN + l0];
#pragma unroll
        for (int l = 0; l < 32; l += 4)
            *(float4*)&op[l] = make_float4(o[l], o[l + 1], o[l + 2], o[l + 3]);
    }
}

extern "C" void kernel_launch(void* const* d_in, const int* in_sizes, int n_in,
                              void* d_out, int out_size, void* d_ws, size_t ws_size,
                              hipStream_t stream) {
    const float* x   = (const float*)d_in[0];
    const int*   ei  = (const int*)d_in[1];
    const float* W1  = (const float*)d_in[2];
    const float* g1  = (const float*)d_in[4];
    const float* be1 = (const float*)d_in[5];
    const float* W2  = (const float*)d_in[6];
    const float* g2  = (const float*)d_in[8];
    const float* be2 = (const float*)d_in[9];
    const float* W3  = (const float*)d_in[10];
    const float* g3  = (const float*)d_in[12];
    const float* be3 = (const float*)d_in[13];
    const int* srcp = ei;
    const int* dstp = ei + EE;

    char* ws = (char*)d_ws;
    size_t pos = 0;
    auto alloc = [&](size_t bytes) -> void* {
        void* p = ws + pos;
        pos = (pos + bytes + 255) & ~(size_t)255;
        return p;
    };
    const size_t big = (size_t)LN * GG * CH * sizeof(unsigned short);  // 33.55 MB
    unsigned short* aB  = (unsigned short*)alloc(big);
    unsigned short* Wp1 = (unsigned short*)alloc(C_0 * CH * 2);
    unsigned short* Wp2 = (unsigned short*)alloc(CH * CH * 2);
    unsigned short* Wp3 = (unsigned short*)alloc(CH * CH * 2);
    int*   offA  = (int*)alloc((LN + 1) * 4);
    float* selfc = (float*)alloc(LN * 4);
    ull*   epack = (ull*)alloc(EE * 8);
    float* varK3 = (float*)alloc(3 * VK * CH * 4);
    unsigned short* hw = (ws_size >= pos + big) ? (unsigned short*)alloc(big)
                                                : (unsigned short*)d_out;

    // one consolidated preprocessing dispatch
    k_prep<<<7, 256, 0, stream>>>(srcp, dstp, W1, W2, W3, selfc, offA, epack,
                                  Wp1, Wp2, Wp3, varK3);

    dim3 mmG(LN / 64, GG);
    const int gnvG = (LN / GNB) * 8;
    float* vK1 = varK3;
    float* vK2 = varK3 + VK * CH;
    float* vK3 = varK3 + 2 * VK * CH;

    // ---- layer 1 ----
    k_mm<C_0, false><<<mmG, 256, 0, stream>>>(x, nullptr, nullptr, nullptr, nullptr,
                                              Wp1, hw);
    k_gnv<<<gnvG, 256, 0, stream>>>(hw, aB, vK1, offA, epack, selfc);

    // ---- layer 2 (layer-1 BN/ReLU fused into staging, scl from vK1) ----
    k_mm<CH, true><<<mmG, 256, 0, stream>>>(nullptr, aB, vK1, g1, be1, Wp2, hw);
    k_gnv<<<gnvG, 256, 0, stream>>>(hw, aB, vK2, offA, epack, selfc);

    // ---- layer 3 ----
    k_mm<CH, true><<<mmG, 256, 0, stream>>>(nullptr, aB, vK2, g2, be2, Wp3, hw);
    k_gnv<<<gnvG, 256, 0, stream>>>(hw, aB, vK3, offA, epack, selfc);

    // ---- output (scl from vK3 computed in-block) ----
    k_epi_t<<<64 * 2 * 8, 256, 0, stream>>>(aB, vK3, g3, be3, (float*)d_out);
}

// Round 9
// 233.757 us; speedup vs baseline: 1.0942x; 1.0942x over previous
//
#include <hip/hip_runtime.h>
#include <hip/hip_bf16.h>

#define GG 64      // B*N graphs
#define LN 2048    // nodes per graph
#define BB 4       // batch
#define NS 16      // sets per batch
#define EE 16384   // edges
#define C_0 64
#define CH 128
#define EPSV 1e-5f
#define VK 16      // variance atomic spread copies
#define GNB 8      // nodes per k_gnv chunk
#define ECAP 384   // staged-edge capacity per chunk (mean 64; global fallback beyond)
// sliced layout: 8 slices of (32 graphs x 32 ch); slice id = (g>>5)*4 + (c>>5)
// elem addr = sid*SLICE + l*1024 + (g&31)*32 + (c&31)
#define SLICE ((size_t)LN * 1024)

using bf16x8 = __attribute__((ext_vector_type(8))) short;
using f32x4  = __attribute__((ext_vector_type(4))) float;
using u32x4  = __attribute__((ext_vector_type(4))) unsigned int;
typedef unsigned long long ull;

__device__ __forceinline__ float b2f(unsigned short u) {
    union { unsigned int i; float f; } v; v.i = ((unsigned int)u) << 16; return v.f;
}
__device__ __forceinline__ unsigned short f2b(float f) {
    union { float f; unsigned int i; } v; v.f = f;
    unsigned int r = v.i + 0x7fffu + ((v.i >> 16) & 1u);   // RNE
    return (unsigned short)(r >> 16);
}
__device__ __forceinline__ void acc8(float* acc, u32x4 v, float w) {
    acc[0] += w * b2f((unsigned short)(v.x & 0xffffu));
    acc[1] += w * b2f((unsigned short)(v.x >> 16));
    acc[2] += w * b2f((unsigned short)(v.y & 0xffffu));
    acc[3] += w * b2f((unsigned short)(v.y >> 16));
    acc[4] += w * b2f((unsigned short)(v.z & 0xffffu));
    acc[5] += w * b2f((unsigned short)(v.z >> 16));
    acc[6] += w * b2f((unsigned short)(v.w & 0xffffu));
    acc[7] += w * b2f((unsigned short)(v.w >> 16));
}
// W permute: element (k,c) -> Wp[(ks*8+nf)*512 + (hi*16+lr)*8 + j]
__device__ __forceinline__ void wprep_one(const float* __restrict__ W,
                                          unsigned short* __restrict__ Wp, int idx) {
    int k = idx >> 7, c = idx & (CH - 1);
    int nf = c >> 4, lr = c & 15, ks = k >> 5, hi = (k >> 3) & 3, j = k & 7;
    Wp[(ks * 8 + nf) * 512 + (hi * 16 + lr) * 8 + j] = f2b(W[idx]);
}

// ---------- prep A: order-free work in one dispatch ----------
// blocks 0,6: zero cnt/cur/varK3; 1: Wp1; 2-3: Wp2; 4-5: Wp3
__global__ __launch_bounds__(256) void k_prep_a(
    const float* __restrict__ W1, const float* __restrict__ W2,
    const float* __restrict__ W3, unsigned short* __restrict__ Wp1,
    unsigned short* __restrict__ Wp2, unsigned short* __restrict__ Wp3,
    int* __restrict__ cnt, int* __restrict__ cur, float* __restrict__ varK3)
{
    const int bid = blockIdx.x;
    const int t = threadIdx.x;
    if (bid == 0) {
        for (int i = t; i < LN; i += 256) { cnt[i] = 0; cur[i] = 0; }
    } else if (bid == 1) {
        for (int i = t; i < C_0 * CH; i += 256) wprep_one(W1, Wp1, i);
    } else if (bid <= 3) {
        const int base = (bid - 2) * 8192;
        for (int i = t; i < 8192; i += 256) wprep_one(W2, Wp2, base + i);
    } else if (bid <= 5) {
        const int base = (bid - 4) * 8192;
        for (int i = t; i < 8192; i += 256) wprep_one(W3, Wp3, base + i);
    } else {
        for (int i = t; i < 3 * VK * CH; i += 256) varK3[i] = 0.f;
    }
}

__global__ void k_deg(const int* __restrict__ dst, int* __restrict__ cnt) {
    int e = blockIdx.x * blockDim.x + threadIdx.x;
    if (e < EE) atomicAdd(&cnt[dst[e]], 1);
}

// node coefficients + CSR scan (single block; 2048 elements)
__global__ __launch_bounds__(256) void k_nscan(
    const int* __restrict__ cnt, float* __restrict__ dinv,
    float* __restrict__ selfc, int* __restrict__ off)
{
    __shared__ int part[256];
    __shared__ int pre2[256];
    const int t = threadIdx.x;
    const int base = t * 8;
    int loc[8];
    int s = 0;
#pragma unroll
    for (int i = 0; i < 8; i++) {
        loc[i] = cnt[base + i];
        s += loc[i];
        float d = (float)loc[i] + 2.0f;   // improved GCN: A + 2I
        float di = rsqrtf(d);
        dinv[base + i] = di;
        selfc[base + i] = 2.0f * di * di;
    }
    part[t] = s;
    __syncthreads();
    if (t == 0) {
        int run = 0;
        for (int i = 0; i < 256; i++) { pre2[i] = run; run += part[i]; }
        off[LN] = run;
    }
    __syncthreads();
    int run = pre2[t];
#pragma unroll
    for (int i = 0; i < 8; i++) { off[base + i] = run; run += loc[i]; }
}

// pack (src, norm) into one 8-byte word per edge (parallel, global cur atomics)
__global__ void k_fill(const int* __restrict__ src, const int* __restrict__ dst,
                       const int* __restrict__ off, int* __restrict__ cur,
                       const float* __restrict__ dinv, ull* __restrict__ epack) {
    int e = blockIdx.x * blockDim.x + threadIdx.x;
    if (e < EE) {
        int s = src[e], d = dst[e];
        int pos = atomicAdd(&cur[d], 1);
        union { float f; unsigned u; } w;
        w.f = dinv[s] * dinv[d];
        epack[off[d] + pos] = (ull)(unsigned)s | ((ull)w.u << 32);
    }
}

// ---------- MFMA GEMM: hw[l,g,co] = sum_k A[l,k] * W[k,co] (bf16, fp32 acc) ----------
// FUSE=false: layer 1, A from x fp32 [g][K][LN] via LDS transpose.
// FUSE=true : A-fragment direct from sliced global aB (16B/lane contiguous);
//             previous layer's BN scale computed in-block from varK, BN+ReLU in regs.
template <int K, bool FUSE>
__global__ __launch_bounds__(256) void k_mm(
    const float* __restrict__ X, const unsigned short* __restrict__ Ap,
    const float* __restrict__ varKp, const float* __restrict__ gam,
    const float* __restrict__ bet,
    const unsigned short* __restrict__ Wp, unsigned short* __restrict__ hw)
{
    constexpr int KP = K + 8;                 // LDS k-pad (!FUSE staging)
    __shared__ unsigned short As[64 * 136];   // A tile (!FUSE) / C repack buffer
    __shared__ float sclL[CH];
    const int g = blockIdx.y;
    const int l0 = blockIdx.x * 64;
    const int t = threadIdx.x;
    const int wq = t >> 6;
    const int lane = t & 63;
    const int lr = lane & 15;
    const int hi = lane >> 4;
    const int kof = hi * 8;

    f32x4 acc[8];
#pragma unroll
    for (int i = 0; i < 8; i++) acc[i] = (f32x4){0.f, 0.f, 0.f, 0.f};

    if (FUSE) {
        if (t < CH) {
            float v = 0.f;
#pragma unroll
            for (int k = 0; k < VK; k++) v += varKp[k * CH + t];
            sclL[t] = gam[t] * rsqrtf(v * (1.f / (GG * LN)) + EPSV);
        }
        __syncthreads();
        const int sg = g >> 5;
        const int gi = g & 31;
        const int row = l0 + wq * 16 + lr;
        bf16x8 aF[K / 32];
#pragma unroll
        for (int ks = 0; ks < K / 32; ks++) {
            const unsigned short* ap = Ap + (size_t)(sg * 4 + ks) * SLICE +
                                       (size_t)row * 1024 + gi * 32 + kof;
            union { uint4 v; unsigned short s[8]; } u;
            u.v = *(const uint4*)ap;
            const int cb = ks * 32 + kof;
            float4 s0 = *(const float4*)&sclL[cb];
            float4 s1 = *(const float4*)&sclL[cb + 4];
            float4 c0 = *(const float4*)&bet[cb];
            float4 c1 = *(const float4*)&bet[cb + 4];
            union { bf16x8 f; unsigned short s[8]; } o;
            o.s[0] = f2b(fmaxf(b2f(u.s[0]) * s0.x + c0.x, 0.f));
            o.s[1] = f2b(fmaxf(b2f(u.s[1]) * s0.y + c0.y, 0.f));
            o.s[2] = f2b(fmaxf(b2f(u.s[2]) * s0.z + c0.z, 0.f));
            o.s[3] = f2b(fmaxf(b2f(u.s[3]) * s0.w + c0.w, 0.f));
            o.s[4] = f2b(fmaxf(b2f(u.s[4]) * s1.x + c1.x, 0.f));
            o.s[5] = f2b(fmaxf(b2f(u.s[5]) * s1.y + c1.y, 0.f));
            o.s[6] = f2b(fmaxf(b2f(u.s[6]) * s1.z + c1.z, 0.f));
            o.s[7] = f2b(fmaxf(b2f(u.s[7]) * s1.w + c1.w, 0.f));
            aF[ks] = o.f;
        }
#pragma unroll
        for (int ks = 0; ks < K / 32; ks++) {
#pragma unroll
            for (int nf = 0; nf < 8; nf++) {
                bf16x8 bF = *(const bf16x8*)&Wp[(ks * 8 + nf) * 512 + lane * 8];
                acc[nf] = __builtin_amdgcn_mfma_f32_16x16x32_bf16(aF[ks], bF,
                                                                  acc[nf], 0, 0, 0);
            }
        }
    } else {
        // x fp32 [g][K][LN] -> As[l][k] bf16 (transpose in LDS)
        const int k = t >> 2;
        const int lq = (t & 3) * 16;
        const float* xp = X + ((size_t)g * K + k) * LN + l0 + lq;
#pragma unroll
        for (int i = 0; i < 16; i += 4) {
            float4 v = *(const float4*)&xp[i];
            As[(lq + i + 0) * KP + k] = f2b(v.x);
            As[(lq + i + 1) * KP + k] = f2b(v.y);
            As[(lq + i + 2) * KP + k] = f2b(v.z);
            As[(lq + i + 3) * KP + k] = f2b(v.w);
        }
        __syncthreads();
#pragma unroll
        for (int ks = 0; ks < K / 32; ks++) {
            bf16x8 aF = *(const bf16x8*)&As[(wq * 16 + lr) * KP + ks * 32 + kof];
#pragma unroll
            for (int nf = 0; nf < 8; nf++) {
                bf16x8 bF = *(const bf16x8*)&Wp[(ks * 8 + nf) * 512 + lane * 8];
                acc[nf] = __builtin_amdgcn_mfma_f32_16x16x32_bf16(aF, bF,
                                                                  acc[nf], 0, 0, 0);
            }
        }
        __syncthreads();   // As about to be overwritten by C repack
    }
    // repack D (C/D map: col=lane&15, row=(lane>>4)*4+reg) into As
#pragma unroll
    for (int nf = 0; nf < 8; nf++) {
#pragma unroll
        for (int r = 0; r < 4; r++) {
            int row = wq * 16 + (lane >> 4) * 4 + r;
            int col = nf * 16 + lr;
            As[row * 136 + col] = f2b(acc[nf][r]);
        }
    }
    __syncthreads();
    {
        const int l = t >> 2;
        const int sc = t & 3;
        unsigned short* hp = hw + (size_t)((g >> 5) * 4 + sc) * SLICE +
                             (size_t)(l0 + l) * 1024 + (g & 31) * 32;
#pragma unroll
        for (int i = 0; i < 32; i += 8)
            *(uint4*)&hp[i] = *(const uint4*)&As[l * 136 + sc * 32 + i];
    }
}

// ---------- fused gather + center + variance, XCD-pinned slices ----------
// bid = chunk*8 + sid; GNB nodes per chunk; 256 threads = 2 rows x 128 lanes (16B)
// edge metadata staged in LDS up front -> gather addresses have no global dependency
__global__ __launch_bounds__(256) void k_gnv(
    const unsigned short* __restrict__ hw, unsigned short* __restrict__ a,
    float* __restrict__ varK, const int* __restrict__ off,
    const ull* __restrict__ epack, const float* __restrict__ selfc)
{
    __shared__ ull emeta[ECAP];
    __shared__ int soff[GNB + 1];
    __shared__ float sselfc[GNB];
    __shared__ float vred[4][32];
    const int bid = blockIdx.x;
    const int sid = bid & 7;
    const int chunk = bid >> 3;          // [0, LN/GNB)
    const int l0 = chunk * GNB;
    const int t = threadIdx.x;
    const int tr = t >> 7;
    const int ti = t & 127;
    const int lane = t & 63;
    const int wq = t >> 6;
    const int go = ti * 8;               // short offset within 1024-short row
    const unsigned short* hws = hw + sid * SLICE;
    unsigned short* aBs = a + sid * SLICE;

    // prefetch self rows (independent of LDS)
    u32x4 v0s[GNB / 2];
#pragma unroll
    for (int ii = 0; ii < GNB / 2; ii++)
        v0s[ii] = *(const u32x4*)&hws[(size_t)(l0 + ii * 2 + tr) * 1024 + go];

    // stage metadata
    const int e0 = off[l0];
    const int eTot = off[l0 + GNB] - e0;
    if (t <= GNB) soff[t] = off[l0 + t];
    if (t >= 32 && t < 32 + GNB) sselfc[t - 32] = selfc[l0 + t - 32];
    const int estg = eTot < ECAP ? eTot : ECAP;
    for (int i = t; i < estg; i += 256) emeta[i] = epack[e0 + i];
    __syncthreads();

    float vacc[8] = {0.f, 0.f, 0.f, 0.f, 0.f, 0.f, 0.f, 0.f};

    auto gather = [&](const ull* __restrict__ mp) {
#pragma unroll
        for (int ii = 0; ii < GNB / 2; ii++) {
            const int ln = ii * 2 + tr;
            const int l = l0 + ln;
            const int s0 = soff[ln] - e0;
            const int s1 = soff[ln + 1] - e0;
            const float sc = sselfc[ln];
            float acc[8];
            {
                u32x4 v0 = v0s[ii];
                acc[0] = sc * b2f((unsigned short)(v0.x & 0xffffu));
                acc[1] = sc * b2f((unsigned short)(v0.x >> 16));
                acc[2] = sc * b2f((unsigned short)(v0.y & 0xffffu));
                acc[3] = sc * b2f((unsigned short)(v0.y >> 16));
                acc[4] = sc * b2f((unsigned short)(v0.z & 0xffffu));
                acc[5] = sc * b2f((unsigned short)(v0.z >> 16));
                acc[6] = sc * b2f((unsigned short)(v0.w & 0xffffu));
                acc[7] = sc * b2f((unsigned short)(v0.w >> 16));
            }
            int e = s0;
            for (; e + 4 <= s1; e += 4) {
                ull m0 = mp[e], m1 = mp[e + 1], m2 = mp[e + 2], m3 = mp[e + 3];
                u32x4 vA = *(const u32x4*)&hws[(size_t)(unsigned)m0 * 1024 + go];
                u32x4 vB = *(const u32x4*)&hws[(size_t)(unsigned)m1 * 1024 + go];
                u32x4 vC = *(const u32x4*)&hws[(size_t)(unsigned)m2 * 1024 + go];
                u32x4 vD = *(const u32x4*)&hws[(size_t)(unsigned)m3 * 1024 + go];
                acc8(acc, vA, __uint_as_float((unsigned)(m0 >> 32)));
                acc8(acc, vB, __uint_as_float((unsigned)(m1 >> 32)));
                acc8(acc, vC, __uint_as_float((unsigned)(m2 >> 32)));
                acc8(acc, vD, __uint_as_float((unsigned)(m3 >> 32)));
            }
            for (; e < s1; e++) {
                ull m0 = mp[e];
                u32x4 vA = *(const u32x4*)&hws[(size_t)(unsigned)m0 * 1024 + go];
                acc8(acc, vA, __uint_as_float((unsigned)(m0 >> 32)));
            }
            // mean over the 16 sets (n-index = lane bits 2..5)
            float m[8];
#pragma unroll
            for (int j = 0; j < 8; j++) m[j] = acc[j];
#pragma unroll
            for (int mask = 4; mask <= 32; mask <<= 1) {
#pragma unroll
                for (int j = 0; j < 8; j++) m[j] += __shfl_xor(m[j], mask);
            }
            u32x4 o;
            unsigned short ob[8];
#pragma unroll
            for (int j = 0; j < 8; j++) {
                float d = acc[j] - m[j] * (1.f / NS);   // centered value
                vacc[j] += d * d;
                ob[j] = f2b(d);
            }
            o.x = (unsigned int)ob[0] | ((unsigned int)ob[1] << 16);
            o.y = (unsigned int)ob[2] | ((unsigned int)ob[3] << 16);
            o.z = (unsigned int)ob[4] | ((unsigned int)ob[5] << 16);
            o.w = (unsigned int)ob[6] | ((unsigned int)ob[7] << 16);
            __builtin_nontemporal_store(o, (u32x4*)&aBs[(size_t)l * 1024 + go]);
        }
    };
    if (eTot <= ECAP) gather(emeta);
    else gather(epack + e0);           // pathological-degree fallback (never in practice)

    // variance: butterfly within wave, cross-wave LDS reduce, 32 atomics/block
#pragma unroll
    for (int mask = 4; mask <= 32; mask <<= 1) {
#pragma unroll
        for (int j = 0; j < 8; j++) vacc[j] += __shfl_xor(vacc[j], mask);
    }
    if (lane < 4) {
#pragma unroll
        for (int j = 0; j < 8; j++) vred[wq][lane * 8 + j] = vacc[j];
    }
    __syncthreads();
    if (t < 32) {
        float s = vred[0][t] + vred[1][t] + vred[2][t] + vred[3][t];
        atomicAdd(&varK[(chunk & (VK - 1)) * CH + (sid & 3) * 32 + t], s);
    }
}

// ---------- final epilogue: sliced centered bf16 -> out[g][c][l] fp32 ----------
// bid = ((chunk*2 + gh)*8) + sid; chunk picks 32 nodes, gh picks 16-graph half
// 128B fully-coalesced output segments; BN scale computed in-block from varK
__global__ __launch_bounds__(256) void k_epi_t(
    const unsigned short* __restrict__ a, const float* __restrict__ varKp,
    const float* __restrict__ gam, const float* __restrict__ bet,
    float* __restrict__ out)
{
    __shared__ unsigned short lds[32 * 16 * 40];   // [l][g][c pad40], 40KB
    __shared__ float sclL[CH];
    const int bid = blockIdx.x;
    const int sid = bid & 7;
    const int q = bid >> 3;              // chunk*2 + gh
    const int gh = q & 1;
    const int chunk = q >> 1;            // [0,64)
    const int l0 = chunk * 32;
    const int t = threadIdx.x;
    const int sg = sid >> 2;
    const int sc = sid & 3;
    const unsigned short* aBs = a + sid * SLICE;
    if (t < CH) {
        float v = 0.f;
#pragma unroll
        for (int k = 0; k < VK; k++) v += varKp[k * CH + t];
        sclL[t] = gam[t] * rsqrtf(v * (1.f / (GG * LN)) + EPSV);
    }
    {
        const int qr = t >> 6;           // 4 rows in flight
        const int ti = t & 63;
        const int gl = ti >> 2;
        const int c0 = (ti & 3) * 8;
#pragma unroll
        for (int i = 0; i < 8; i++) {
            const int lrow = i * 4 + qr;
            uint4 v = *(const uint4*)&aBs[(size_t)(l0 + lrow) * 1024 + gh * 512 + ti * 8];
            *(uint4*)&lds[(lrow * 16 + gl) * 40 + c0] = v;
        }
    }
    __syncthreads();
#pragma unroll
    for (int it = 0; it < 2; it++) {
        const int p = it * 256 + t;
        const int g2 = p >> 5;           // [0,16)
        const int c2 = p & 31;
        const int cG = sc * 32 + c2;
        const int gG = sg * 32 + gh * 16 + g2;
        const float s = sclL[cG], bb = bet[cG];
        float o[32];
#pragma unroll
        for (int l = 0; l < 32; l++)
            o[l] = fmaxf(b2f(lds[(l * 16 + g2) * 40 + c2]) * s + bb, 0.f);
        float* op = &out[((size_t)gG * CH + cG) * LN + l0];
#pragma unroll
        for (int l = 0; l < 32; l += 4)
            *(float4*)&op[l] = make_float4(o[l], o[l + 1], o[l + 2], o[l + 3]);
    }
}

extern "C" void kernel_launch(void* const* d_in, const int* in_sizes, int n_in,
                              void* d_out, int out_size, void* d_ws, size_t ws_size,
                              hipStream_t stream) {
    const float* x   = (const float*)d_in[0];
    const int*   ei  = (const int*)d_in[1];
    const float* W1  = (const float*)d_in[2];
    const float* g1  = (const float*)d_in[4];
    const float* be1 = (const float*)d_in[5];
    const float* W2  = (const float*)d_in[6];
    const float* g2  = (const float*)d_in[8];
    const float* be2 = (const float*)d_in[9];
    const float* W3  = (const float*)d_in[10];
    const float* g3  = (const float*)d_in[12];
    const float* be3 = (const float*)d_in[13];
    const int* srcp = ei;
    const int* dstp = ei + EE;

    char* ws = (char*)d_ws;
    size_t pos = 0;
    auto alloc = [&](size_t bytes) -> void* {
        void* p = ws + pos;
        pos = (pos + bytes + 255) & ~(size_t)255;
        return p;
    };
    const size_t big = (size_t)LN * GG * CH * sizeof(unsigned short);  // 33.55 MB
    unsigned short* aB  = (unsigned short*)alloc(big);
    unsigned short* Wp1 = (unsigned short*)alloc(C_0 * CH * 2);
    unsigned short* Wp2 = (unsigned short*)alloc(CH * CH * 2);
    unsigned short* Wp3 = (unsigned short*)alloc(CH * CH * 2);
    int*   cnt   = (int*)alloc(LN * 4);
    int*   cur   = (int*)alloc(LN * 4);
    int*   offA  = (int*)alloc((LN + 1) * 4);
    float* dinv  = (float*)alloc(LN * 4);
    float* selfc = (float*)alloc(LN * 4);
    ull*   epack = (ull*)alloc(EE * 8);
    float* varK3 = (float*)alloc(3 * VK * CH * 4);
    unsigned short* hw = (ws_size >= pos + big) ? (unsigned short*)alloc(big)
                                                : (unsigned short*)d_out;

    // preprocessing: parallel phases, ordering only where required
    k_prep_a<<<7, 256, 0, stream>>>(W1, W2, W3, Wp1, Wp2, Wp3, cnt, cur, varK3);
    k_deg<<<EE / 256, 256, 0, stream>>>(dstp, cnt);
    k_nscan<<<1, 256, 0, stream>>>(cnt, dinv, selfc, offA);
    k_fill<<<EE / 256, 256, 0, stream>>>(srcp, dstp, offA, cur, dinv, epack);

    dim3 mmG(LN / 64, GG);
    const int gnvG = (LN / GNB) * 8;
    float* vK1 = varK3;
    float* vK2 = varK3 + VK * CH;
    float* vK3 = varK3 + 2 * VK * CH;

    // ---- layer 1 ----
    k_mm<C_0, false><<<mmG, 256, 0, stream>>>(x, nullptr, nullptr, nullptr, nullptr,
                                              Wp1, hw);
    k_gnv<<<gnvG, 256, 0, stream>>>(hw, aB, vK1, offA, epack, selfc);

    // ---- layer 2 (layer-1 BN/ReLU fused into staging, scl from vK1) ----
    k_mm<CH, true><<<mmG, 256, 0, stream>>>(nullptr, aB, vK1, g1, be1, Wp2, hw);
    k_gnv<<<gnvG, 256, 0, stream>>>(hw, aB, vK2, offA, epack, selfc);

    // ---- layer 3 ----
    k_mm<CH, true><<<mmG, 256, 0, stream>>>(nullptr, aB, vK2, g2, be2, Wp3, hw);
    k_gnv<<<gnvG, 256, 0, stream>>>(hw, aB, vK3, offA, epack, selfc);

    // ---- output (scl from vK3 computed in-block) ----
    k_epi_t<<<64 * 2 * 8, 256, 0, stream>>>(aB, vK3, g3, be3, (float*)d_out);
}

// Round 10
// 230.780 us; speedup vs baseline: 1.1083x; 1.0129x over previous
//
#include <hip/hip_runtime.h>
#include <hip/hip_bf16.h>

#define GG 64      // B*N graphs
#define LN 2048    // nodes per graph
#define BB 4       // batch
#define NS 16      // sets per batch
#define EE 16384   // edges
#define C_0 64
#define CH 128
#define EPSV 1e-5f
#define VK 16      // variance atomic spread copies
#define GNB 8      // nodes per k_gnv chunk
#define ECAP 384   // staged-edge capacity per chunk (mean 64; global fallback beyond)
// sliced layout: 8 slices of (32 graphs x 32 ch); slice id = (g>>5)*4 + (c>>5)
// elem addr = sid*SLICE + l*1024 + (g&31)*32 + (c&31)
#define SLICE ((size_t)LN * 1024)

using bf16x8 = __attribute__((ext_vector_type(8))) short;
using f32x4  = __attribute__((ext_vector_type(4))) float;
using u32x4  = __attribute__((ext_vector_type(4))) unsigned int;
typedef unsigned long long ull;

__device__ __forceinline__ float b2f(unsigned short u) {
    union { unsigned int i; float f; } v; v.i = ((unsigned int)u) << 16; return v.f;
}
__device__ __forceinline__ unsigned short f2b(float f) {
    union { float f; unsigned int i; } v; v.f = f;
    unsigned int r = v.i + 0x7fffu + ((v.i >> 16) & 1u);   // RNE
    return (unsigned short)(r >> 16);
}
__device__ __forceinline__ void acc8(float* acc, u32x4 v, float w) {
    acc[0] += w * b2f((unsigned short)(v.x & 0xffffu));
    acc[1] += w * b2f((unsigned short)(v.x >> 16));
    acc[2] += w * b2f((unsigned short)(v.y & 0xffffu));
    acc[3] += w * b2f((unsigned short)(v.y >> 16));
    acc[4] += w * b2f((unsigned short)(v.z & 0xffffu));
    acc[5] += w * b2f((unsigned short)(v.z >> 16));
    acc[6] += w * b2f((unsigned short)(v.w & 0xffffu));
    acc[7] += w * b2f((unsigned short)(v.w >> 16));
}
// W permute: element (k,c) -> Wp[(ks*8+nf)*512 + (hi*16+lr)*8 + j]
__device__ __forceinline__ void wprep_one(const float* __restrict__ W,
                                          unsigned short* __restrict__ Wp, int idx) {
    int k = idx >> 7, c = idx & (CH - 1);
    int nf = c >> 4, lr = c & 15, ks = k >> 5, hi = (k >> 3) & 3, j = k & 7;
    Wp[(ks * 8 + nf) * 512 + (hi * 16 + lr) * 8 + j] = f2b(W[idx]);
}

// ---------- prep A: order-free work in one dispatch ----------
__global__ __launch_bounds__(256) void k_prep_a(
    const float* __restrict__ W1, const float* __restrict__ W2,
    const float* __restrict__ W3, unsigned short* __restrict__ Wp1,
    unsigned short* __restrict__ Wp2, unsigned short* __restrict__ Wp3,
    int* __restrict__ cnt, int* __restrict__ cur, float* __restrict__ varK3)
{
    const int bid = blockIdx.x;
    const int t = threadIdx.x;
    if (bid == 0) {
        for (int i = t; i < LN; i += 256) { cnt[i] = 0; cur[i] = 0; }
    } else if (bid == 1) {
        for (int i = t; i < C_0 * CH; i += 256) wprep_one(W1, Wp1, i);
    } else if (bid <= 3) {
        const int base = (bid - 2) * 8192;
        for (int i = t; i < 8192; i += 256) wprep_one(W2, Wp2, base + i);
    } else if (bid <= 5) {
        const int base = (bid - 4) * 8192;
        for (int i = t; i < 8192; i += 256) wprep_one(W3, Wp3, base + i);
    } else {
        for (int i = t; i < 3 * VK * CH; i += 256) varK3[i] = 0.f;
    }
}

__global__ void k_deg(const int* __restrict__ dst, int* __restrict__ cnt) {
    int e = blockIdx.x * blockDim.x + threadIdx.x;
    if (e < EE) atomicAdd(&cnt[dst[e]], 1);
}

// node coefficients + CSR scan (single block; 2048 elements)
__global__ __launch_bounds__(256) void k_nscan(
    const int* __restrict__ cnt, float* __restrict__ dinv,
    float* __restrict__ selfc, int* __restrict__ off)
{
    __shared__ int part[256];
    __shared__ int pre2[256];
    const int t = threadIdx.x;
    const int base = t * 8;
    int loc[8];
    int s = 0;
#pragma unroll
    for (int i = 0; i < 8; i++) {
        loc[i] = cnt[base + i];
        s += loc[i];
        float d = (float)loc[i] + 2.0f;   // improved GCN: A + 2I
        float di = rsqrtf(d);
        dinv[base + i] = di;
        selfc[base + i] = 2.0f * di * di;
    }
    part[t] = s;
    __syncthreads();
    if (t == 0) {
        int run = 0;
        for (int i = 0; i < 256; i++) { pre2[i] = run; run += part[i]; }
        off[LN] = run;
    }
    __syncthreads();
    int run = pre2[t];
#pragma unroll
    for (int i = 0; i < 8; i++) { off[base + i] = run; run += loc[i]; }
}

// pack (src, norm) into one 8-byte word per edge (parallel, global cur atomics)
__global__ void k_fill(const int* __restrict__ src, const int* __restrict__ dst,
                       const int* __restrict__ off, int* __restrict__ cur,
                       const float* __restrict__ dinv, ull* __restrict__ epack) {
    int e = blockIdx.x * blockDim.x + threadIdx.x;
    if (e < EE) {
        int s = src[e], d = dst[e];
        int pos = atomicAdd(&cur[d], 1);
        union { float f; unsigned u; } w;
        w.f = dinv[s] * dinv[d];
        epack[off[d] + pos] = (ull)(unsigned)s | ((ull)w.u << 32);
    }
}

// ---------- MFMA GEMM: hw[l,g,co] = sum_k A[l,k] * W[k,co] (bf16, fp32 acc) ----------
// FUSE=false: layer 1, A-fragments loaded DIRECTLY from x fp32 [g][K][LN] at stride LN
//             (no LDS staging, no extra barrier).
// FUSE=true : A-fragment direct from sliced global aB (16B/lane contiguous);
//             previous layer's BN scale computed in-block from varK, BN+ReLU in regs.
template <int K, bool FUSE>
__global__ __launch_bounds__(256) void k_mm(
    const float* __restrict__ X, const unsigned short* __restrict__ Ap,
    const float* __restrict__ varKp, const float* __restrict__ gam,
    const float* __restrict__ bet,
    const unsigned short* __restrict__ Wp, unsigned short* __restrict__ hw)
{
    __shared__ unsigned short Cs[64 * 136];   // C repack buffer
    __shared__ float sclL[CH];
    const int g = blockIdx.y;
    const int l0 = blockIdx.x * 64;
    const int t = threadIdx.x;
    const int wq = t >> 6;
    const int lane = t & 63;
    const int lr = lane & 15;
    const int hi = lane >> 4;
    const int kof = hi * 8;
    const int row = l0 + wq * 16 + lr;

    bf16x8 aF[K / 32];
    if (FUSE) {
        if (t < CH) {
            float v = 0.f;
#pragma unroll
            for (int k = 0; k < VK; k++) v += varKp[k * CH + t];
            sclL[t] = gam[t] * rsqrtf(v * (1.f / (GG * LN)) + EPSV);
        }
        __syncthreads();
        const int sg = g >> 5;
        const int gi = g & 31;
#pragma unroll
        for (int ks = 0; ks < K / 32; ks++) {
            const unsigned short* ap = Ap + (size_t)(sg * 4 + ks) * SLICE +
                                       (size_t)row * 1024 + gi * 32 + kof;
            union { uint4 v; unsigned short s[8]; } u;
            u.v = *(const uint4*)ap;
            const int cb = ks * 32 + kof;
            float4 s0 = *(const float4*)&sclL[cb];
            float4 s1 = *(const float4*)&sclL[cb + 4];
            float4 c0 = *(const float4*)&bet[cb];
            float4 c1 = *(const float4*)&bet[cb + 4];
            union { bf16x8 f; unsigned short s[8]; } o;
            o.s[0] = f2b(fmaxf(b2f(u.s[0]) * s0.x + c0.x, 0.f));
            o.s[1] = f2b(fmaxf(b2f(u.s[1]) * s0.y + c0.y, 0.f));
            o.s[2] = f2b(fmaxf(b2f(u.s[2]) * s0.z + c0.z, 0.f));
            o.s[3] = f2b(fmaxf(b2f(u.s[3]) * s0.w + c0.w, 0.f));
            o.s[4] = f2b(fmaxf(b2f(u.s[4]) * s1.x + c1.x, 0.f));
            o.s[5] = f2b(fmaxf(b2f(u.s[5]) * s1.y + c1.y, 0.f));
            o.s[6] = f2b(fmaxf(b2f(u.s[6]) * s1.z + c1.z, 0.f));
            o.s[7] = f2b(fmaxf(b2f(u.s[7]) * s1.w + c1.w, 0.f));
            aF[ks] = o.f;
        }
    } else {
        // direct strided loads: lane reads its 8 k-values at stride LN
#pragma unroll
        for (int ks = 0; ks < K / 32; ks++) {
            const float* xp = X + ((size_t)g * K + ks * 32 + kof) * LN + row;
            union { bf16x8 f; unsigned short s[8]; } o;
#pragma unroll
            for (int j = 0; j < 8; j++) o.s[j] = f2b(xp[(size_t)j * LN]);
            aF[ks] = o.f;
        }
    }

    f32x4 acc[8];
#pragma unroll
    for (int i = 0; i < 8; i++) acc[i] = (f32x4){0.f, 0.f, 0.f, 0.f};
#pragma unroll
    for (int ks = 0; ks < K / 32; ks++) {
#pragma unroll
        for (int nf = 0; nf < 8; nf++) {
            bf16x8 bF = *(const bf16x8*)&Wp[(ks * 8 + nf) * 512 + lane * 8];
            acc[nf] = __builtin_amdgcn_mfma_f32_16x16x32_bf16(aF[ks], bF,
                                                              acc[nf], 0, 0, 0);
        }
    }
    // repack D (C/D map: col=lane&15, row=(lane>>4)*4+reg); per-wave rows disjoint
#pragma unroll
    for (int nf = 0; nf < 8; nf++) {
#pragma unroll
        for (int r = 0; r < 4; r++) {
            int rr = wq * 16 + (lane >> 4) * 4 + r;
            int col = nf * 16 + lr;
            Cs[rr * 136 + col] = f2b(acc[nf][r]);
        }
    }
    __syncthreads();
    {
        const int l = t >> 2;
        const int sc = t & 3;
        unsigned short* hp = hw + (size_t)((g >> 5) * 4 + sc) * SLICE +
                             (size_t)(l0 + l) * 1024 + (g & 31) * 32;
#pragma unroll
        for (int i = 0; i < 32; i += 8)
            *(uint4*)&hp[i] = *(const uint4*)&Cs[l * 136 + sc * 32 + i];
    }
}

// ---------- fused gather + center + variance, XCD-pinned slices ----------
// bid = chunk*8 + sid; GNB nodes per chunk; 256 threads = 2 rows x 128 lanes (16B)
// edge metadata staged in LDS up front; 8-deep edge unroll (matches mean degree)
__global__ __launch_bounds__(256) void k_gnv(
    const unsigned short* __restrict__ hw, unsigned short* __restrict__ a,
    float* __restrict__ varK, const int* __restrict__ off,
    const ull* __restrict__ epack, const float* __restrict__ selfc)
{
    __shared__ ull emeta[ECAP];
    __shared__ int soff[GNB + 1];
    __shared__ float sselfc[GNB];
    __shared__ float vred[4][32];
    const int bid = blockIdx.x;
    const int sid = bid & 7;
    const int chunk = bid >> 3;          // [0, LN/GNB)
    const int l0 = chunk * GNB;
    const int t = threadIdx.x;
    const int tr = t >> 7;
    const int ti = t & 127;
    const int lane = t & 63;
    const int wq = t >> 6;
    const int go = ti * 8;               // short offset within 1024-short row
    const unsigned short* hws = hw + sid * SLICE;
    unsigned short* aBs = a + sid * SLICE;

    // prefetch self rows (independent of LDS)
    u32x4 v0s[GNB / 2];
#pragma unroll
    for (int ii = 0; ii < GNB / 2; ii++)
        v0s[ii] = *(const u32x4*)&hws[(size_t)(l0 + ii * 2 + tr) * 1024 + go];

    // stage metadata
    const int e0 = off[l0];
    const int eTot = off[l0 + GNB] - e0;
    if (t <= GNB) soff[t] = off[l0 + t];
    if (t >= 32 && t < 32 + GNB) sselfc[t - 32] = selfc[l0 + t - 32];
    const int estg = eTot < ECAP ? eTot : ECAP;
    for (int i = t; i < estg; i += 256) emeta[i] = epack[e0 + i];
    __syncthreads();

    float vacc[8] = {0.f, 0.f, 0.f, 0.f, 0.f, 0.f, 0.f, 0.f};

    auto gather = [&](const ull* __restrict__ mp) {
#pragma unroll
        for (int ii = 0; ii < GNB / 2; ii++) {
            const int ln = ii * 2 + tr;
            const int l = l0 + ln;
            const int s0 = soff[ln] - e0;
            const int s1 = soff[ln + 1] - e0;
            const float sc = sselfc[ln];
            float acc[8];
            {
                u32x4 v0 = v0s[ii];
                acc[0] = sc * b2f((unsigned short)(v0.x & 0xffffu));
                acc[1] = sc * b2f((unsigned short)(v0.x >> 16));
                acc[2] = sc * b2f((unsigned short)(v0.y & 0xffffu));
                acc[3] = sc * b2f((unsigned short)(v0.y >> 16));
                acc[4] = sc * b2f((unsigned short)(v0.z & 0xffffu));
                acc[5] = sc * b2f((unsigned short)(v0.z >> 16));
                acc[6] = sc * b2f((unsigned short)(v0.w & 0xffffu));
                acc[7] = sc * b2f((unsigned short)(v0.w >> 16));
            }
            int e = s0;
            for (; e + 8 <= s1; e += 8) {      // 8 loads in flight
                ull m0 = mp[e],     m1 = mp[e + 1], m2 = mp[e + 2], m3 = mp[e + 3];
                ull m4 = mp[e + 4], m5 = mp[e + 5], m6 = mp[e + 6], m7 = mp[e + 7];
                u32x4 vA = *(const u32x4*)&hws[(size_t)(unsigned)m0 * 1024 + go];
                u32x4 vB = *(const u32x4*)&hws[(size_t)(unsigned)m1 * 1024 + go];
                u32x4 vC = *(const u32x4*)&hws[(size_t)(unsigned)m2 * 1024 + go];
                u32x4 vD = *(const u32x4*)&hws[(size_t)(unsigned)m3 * 1024 + go];
                u32x4 vE = *(const u32x4*)&hws[(size_t)(unsigned)m4 * 1024 + go];
                u32x4 vF = *(const u32x4*)&hws[(size_t)(unsigned)m5 * 1024 + go];
                u32x4 vG = *(const u32x4*)&hws[(size_t)(unsigned)m6 * 1024 + go];
                u32x4 vH = *(const u32x4*)&hws[(size_t)(unsigned)m7 * 1024 + go];
                acc8(acc, vA, __uint_as_float((unsigned)(m0 >> 32)));
                acc8(acc, vB, __uint_as_float((unsigned)(m1 >> 32)));
                acc8(acc, vC, __uint_as_float((unsigned)(m2 >> 32)));
                acc8(acc, vD, __uint_as_float((unsigned)(m3 >> 32)));
                acc8(acc, vE, __uint_as_float((unsigned)(m4 >> 32)));
                acc8(acc, vF, __uint_as_float((unsigned)(m5 >> 32)));
                acc8(acc, vG, __uint_as_float((unsigned)(m6 >> 32)));
                acc8(acc, vH, __uint_as_float((unsigned)(m7 >> 32)));
            }
            for (; e + 2 <= s1; e += 2) {
                ull m0 = mp[e], m1 = mp[e + 1];
                u32x4 vA = *(const u32x4*)&hws[(size_t)(unsigned)m0 * 1024 + go];
                u32x4 vB = *(const u32x4*)&hws[(size_t)(unsigned)m1 * 1024 + go];
                acc8(acc, vA, __uint_as_float((unsigned)(m0 >> 32)));
                acc8(acc, vB, __uint_as_float((unsigned)(m1 >> 32)));
            }
            if (e < s1) {
                ull m0 = mp[e];
                u32x4 vA = *(const u32x4*)&hws[(size_t)(unsigned)m0 * 1024 + go];
                acc8(acc, vA, __uint_as_float((unsigned)(m0 >> 32)));
            }
            // mean over the 16 sets (n-index = lane bits 2..5)
            float m[8];
#pragma unroll
            for (int j = 0; j < 8; j++) m[j] = acc[j];
#pragma unroll
            for (int mask = 4; mask <= 32; mask <<= 1) {
#pragma unroll
                for (int j = 0; j < 8; j++) m[j] += __shfl_xor(m[j], mask);
            }
            u32x4 o;
            unsigned short ob[8];
#pragma unroll
            for (int j = 0; j < 8; j++) {
                float d = acc[j] - m[j] * (1.f / NS);   // centered value
                vacc[j] += d * d;
                ob[j] = f2b(d);
            }
            o.x = (unsigned int)ob[0] | ((unsigned int)ob[1] << 16);
            o.y = (unsigned int)ob[2] | ((unsigned int)ob[3] << 16);
            o.z = (unsigned int)ob[4] | ((unsigned int)ob[5] << 16);
            o.w = (unsigned int)ob[6] | ((unsigned int)ob[7] << 16);
            __builtin_nontemporal_store(o, (u32x4*)&aBs[(size_t)l * 1024 + go]);
        }
    };
    if (eTot <= ECAP) gather(emeta);
    else gather(epack + e0);           // pathological-degree fallback (never in practice)

    // variance: butterfly within wave, cross-wave LDS reduce, 32 atomics/block
#pragma unroll
    for (int mask = 4; mask <= 32; mask <<= 1) {
#pragma unroll
        for (int j = 0; j < 8; j++) vacc[j] += __shfl_xor(vacc[j], mask);
    }
    if (lane < 4) {
#pragma unroll
        for (int j = 0; j < 8; j++) vred[wq][lane * 8 + j] = vacc[j];
    }
    __syncthreads();
    if (t < 32) {
        float s = vred[0][t] + vred[1][t] + vred[2][t] + vred[3][t];
        atomicAdd(&varK[(chunk & (VK - 1)) * CH + (sid & 3) * 32 + t], s);
    }
}

// ---------- final epilogue: sliced centered bf16 -> out[g][c][l] fp32 ----------
__global__ __launch_bounds__(256) void k_epi_t(
    const unsigned short* __restrict__ a, const float* __restrict__ varKp,
    const float* __restrict__ gam, const float* __restrict__ bet,
    float* __restrict__ out)
{
    __shared__ unsigned short lds[32 * 16 * 40];   // [l][g][c pad40], 40KB
    __shared__ float sclL[CH];
    const int bid = blockIdx.x;
    const int sid = bid & 7;
    const int q = bid >> 3;              // chunk*2 + gh
    const int gh = q & 1;
    const int chunk = q >> 1;            // [0,64)
    const int l0 = chunk * 32;
    const int t = threadIdx.x;
    const int sg = sid >> 2;
    const int sc = sid & 3;
    const unsigned short* aBs = a + sid * SLICE;
    if (t < CH) {
        float v = 0.f;
#pragma unroll
        for (int k = 0; k < VK; k++) v += varKp[k * CH + t];
        sclL[t] = gam[t] * rsqrtf(v * (1.f / (GG * LN)) + EPSV);
    }
    {
        const int qr = t >> 6;           // 4 rows in flight
        const int ti = t & 63;
        const int gl = ti >> 2;
        const int c0 = (ti & 3) * 8;
#pragma unroll
        for (int i = 0; i < 8; i++) {
            const int lrow = i * 4 + qr;
            uint4 v = *(const uint4*)&aBs[(size_t)(l0 + lrow) * 1024 + gh * 512 + ti * 8];
            *(uint4*)&lds[(lrow * 16 + gl) * 40 + c0] = v;
        }
    }
    __syncthreads();
#pragma unroll
    for (int it = 0; it < 2; it++) {
        const int p = it * 256 + t;
        const int g2 = p >> 5;           // [0,16)
        const int c2 = p & 31;
        const int cG = sc * 32 + c2;
        const int gG = sg * 32 + gh * 16 + g2;
        const float s = sclL[cG], bb = bet[cG];
        float o[32];
#pragma unroll
        for (int l = 0; l < 32; l++)
            o[l] = fmaxf(b2f(lds[(l * 16 + g2) * 40 + c2]) * s + bb, 0.f);
        float* op = &out[((size_t)gG * CH + cG) * LN + l0];
#pragma unroll
        for (int l = 0; l < 32; l += 4)
            *(float4*)&op[l] = make_float4(o[l], o[l + 1], o[l + 2], o[l + 3]);
    }
}

extern "C" void kernel_launch(void* const* d_in, const int* in_sizes, int n_in,
                              void* d_out, int out_size, void* d_ws, size_t ws_size,
                              hipStream_t stream) {
    const float* x   = (const float*)d_in[0];
    const int*   ei  = (const int*)d_in[1];
    const float* W1  = (const float*)d_in[2];
    const float* g1  = (const float*)d_in[4];
    const float* be1 = (const float*)d_in[5];
    const float* W2  = (const float*)d_in[6];
    const float* g2  = (const float*)d_in[8];
    const float* be2 = (const float*)d_in[9];
    const float* W3  = (const float*)d_in[10];
    const float* g3  = (const float*)d_in[12];
    const float* be3 = (const float*)d_in[13];
    const int* srcp = ei;
    const int* dstp = ei + EE;

    char* ws = (char*)d_ws;
    size_t pos = 0;
    auto alloc = [&](size_t bytes) -> void* {
        void* p = ws + pos;
        pos = (pos + bytes + 255) & ~(size_t)255;
        return p;
    };
    const size_t big = (size_t)LN * GG * CH * sizeof(unsigned short);  // 33.55 MB
    unsigned short* aB  = (unsigned short*)alloc(big);
    unsigned short* Wp1 = (unsigned short*)alloc(C_0 * CH * 2);
    unsigned short* Wp2 = (unsigned short*)alloc(CH * CH * 2);
    unsigned short* Wp3 = (unsigned short*)alloc(CH * CH * 2);
    int*   cnt   = (int*)alloc(LN * 4);
    int*   cur   = (int*)alloc(LN * 4);
    int*   offA  = (int*)alloc((LN + 1) * 4);
    float* dinv  = (float*)alloc(LN * 4);
    float* selfc = (float*)alloc(LN * 4);
    ull*   epack = (ull*)alloc(EE * 8);
    float* varK3 = (float*)alloc(3 * VK * CH * 4);
    unsigned short* hw = (ws_size >= pos + big) ? (unsigned short*)alloc(big)
                                                : (unsigned short*)d_out;

    // preprocessing: parallel phases, ordering only where required
    k_prep_a<<<7, 256, 0, stream>>>(W1, W2, W3, Wp1, Wp2, Wp3, cnt, cur, varK3);
    k_deg<<<EE / 256, 256, 0, stream>>>(dstp, cnt);
    k_nscan<<<1, 256, 0, stream>>>(cnt, dinv, selfc, offA);
    k_fill<<<EE / 256, 256, 0, stream>>>(srcp, dstp, offA, cur, dinv, epack);

    dim3 mmG(LN / 64, GG);
    const int gnvG = (LN / GNB) * 8;
    float* vK1 = varK3;
    float* vK2 = varK3 + VK * CH;
    float* vK3 = varK3 + 2 * VK * CH;

    // ---- layer 1 ----
    k_mm<C_0, false><<<mmG, 256, 0, stream>>>(x, nullptr, nullptr, nullptr, nullptr,
                                              Wp1, hw);
    k_gnv<<<gnvG, 256, 0, stream>>>(hw, aB, vK1, offA, epack, selfc);

    // ---- layer 2 (layer-1 BN/ReLU fused into staging, scl from vK1) ----
    k_mm<CH, true><<<mmG, 256, 0, stream>>>(nullptr, aB, vK1, g1, be1, Wp2, hw);
    k_gnv<<<gnvG, 256, 0, stream>>>(hw, aB, vK2, offA, epack, selfc);

    // ---- layer 3 ----
    k_mm<CH, true><<<mmG, 256, 0, stream>>>(nullptr, aB, vK2, g2, be2, Wp3, hw);
    k_gnv<<<gnvG, 256, 0, stream>>>(hw, aB, vK3, offA, epack, selfc);

    // ---- output (scl from vK3 computed in-block) ----
    k_epi_t<<<64 * 2 * 8, 256, 0, stream>>>(aB, vK3, g3, be3, (float*)d_out);
}